// Round 5
// baseline (1698.453 us; speedup 1.0000x reference)
//
#include <hip/hip_runtime.h>
#include <math.h>

// LSTM: I=5, H=64, L=3, O=1, B=1024, T=256, fp32.
// Round-5 redesign. r4 (1518 us): 62% VALUBusy, 2 barriers/step, 32 broadcast
// ds_read_b128/thread/step, FMA:LDS-read ratio 4. New mapping: thread
// (u = tid>>2, s = tid&3) owns ALL FOUR gate rows (i,f,g~,o) of hidden unit u
// over k-quarter [16s,16s+16):
//   - ratio 16 FMA per b128 read (4x fewer LDS instrs/CU)
//   - k-partials combined across the quad with DPP quad_perm (VALU pipe, free
//     of DS traffic) -> every lane holds all 4 gates -> c,h computed in-lane
//     (c replicated x4 in registers) -> NO gate LDS buffer, ONE barrier/step.
//   - chunk buffer doubles as recurrent state: step tt reads buf[b][tt-1]
//     (wrap TC-1 = previous chunk's last h), writes buf[b][tt]: disjoint, safe.
// Weights: 4 gates x 4 float4 x 2 matrices = 32 named float4 = 128 VGPR.
// __launch_bounds__(256,2) -> 2 blocks/CU (CUDA min-blocks semantics, r2/r4
// evidence) -> 2 waves/EU -> 256 VGPR cap. LDS 69 KB/block.

constexpr int Hh = 64;
constexpr int Tt = 256;   // timesteps
constexpr int In = 5;     // input size
constexpr int TB = 2;     // batch elems per block
constexpr int TC = 64;    // timestep chunk
constexpr int NB = 512;   // blocks (NB*TB = 1024 = B)
constexpr int NT = 256;   // threads per block

__device__ __forceinline__ float sigm(float x) { return 1.0f / (1.0f + __expf(-x)); }
__device__ __forceinline__ float tanh_fast(float x) {
    float ax = fabsf(x);
    float t = __expf(-2.0f * ax);      // in (0,1], no overflow
    float r = (1.0f - t) / (1.0f + t);
    return copysignf(r, x);
}

// quad_perm DPP: sum across the 4 lanes of each quad (s = lane&3)
template<int CTRL>
__device__ __forceinline__ float qp(float v) {
    int r = __builtin_amdgcn_update_dpp(0, __builtin_bit_cast(int, v),
                                        CTRL, 0xF, 0xF, true);
    return __builtin_bit_cast(float, r);
}
__device__ __forceinline__ float quad_sum(float a) {
    a += qp<0xB1>(a);   // quad_perm [1,0,3,2] : xor 1
    a += qp<0x4E>(a);   // quad_perm [2,3,0,1] : xor 2
    return a;
}

#define DOT4(W, H) ((W).x*(H).x + (W).y*(H).y + (W).z*(H).z + (W).w*(H).w)

// 16-element dot: weights w0..w3 (named float4), source pointer (16B-aligned)
#define DOT16(res, W0, W1, W2, W3, PTR) do { \
    const float4* p_ = reinterpret_cast<const float4*>(PTR); \
    float4 hA = p_[0], hB = p_[1], hC = p_[2], hD = p_[3]; \
    res += (DOT4(W0,hA) + DOT4(W1,hB)) + (DOT4(W2,hC) + DOT4(W3,hD)); \
} while (0)

__global__ __launch_bounds__(NT, 2) void lstm3_fused(
    const float* __restrict__ x,
    const float* __restrict__ w_ih0, const float* __restrict__ w_hh0,
    const float* __restrict__ b_ih0, const float* __restrict__ b_hh0,
    const float* __restrict__ w_ih1, const float* __restrict__ w_hh1,
    const float* __restrict__ b_ih1, const float* __restrict__ b_hh1,
    const float* __restrict__ w_ih2, const float* __restrict__ w_hh2,
    const float* __restrict__ b_ih2, const float* __restrict__ b_hh2,
    const float* __restrict__ w_fc,  const float* __restrict__ b_fc,
    float* __restrict__ out, int nch)
{
    __shared__ alignas(16) float buf0[TB][TC][Hh];   // layer0 h chunk (32 KB)
    __shared__ alignas(16) float buf1[TB][TC][Hh];   // layer1 h chunk (32 KB)
    __shared__ alignas(16) float h2b[2][TB][Hh];     // layer2 rolling h (1 KB)
    __shared__ alignas(16) float xs[TB][TC][8];      // staged input chunk (4 KB)

    const int tid = threadIdx.x;
    const int u   = tid >> 2;        // hidden unit 0..63
    const int s   = tid & 3;         // k-quarter
    const int ko  = 16 * s;          // k offset
    const int b0  = blockIdx.x * TB;

    // c-state in registers, replicated across the 4 lanes of each quad
    float c00 = 0.f, c01 = 0.f;   // layer0: batch 0,1
    float c10 = 0.f, c11 = 0.f;   // layer1
    float c20 = 0.f, c21 = 0.f;   // layer2

    // zero-init recurrent sources (buf*[b][TC-1], h2b[0]) — zero everything
    for (int i = tid; i < TB * TC * Hh; i += NT) { ((float*)buf0)[i] = 0.f; ((float*)buf1)[i] = 0.f; }
    for (int i = tid; i < 2 * TB * Hh; i += NT) ((float*)h2b)[i] = 0.f;

    #pragma unroll 1
    for (int chunk = 0; chunk < nch; ++chunk) {
        const int t0 = chunk * TC;

        // ---- stage x chunk: xs[b][t][0..4], pad 5..7 (1024 elems) ----
        for (int i = tid; i < TB * TC * 8; i += NT) {
            int b  = i >> 9;
            int r  = i & 511;
            int t  = r >> 3;
            int cc = r & 7;
            xs[b][t][cc] = (cc < In)
                ? x[((size_t)(b0 + b) * Tt + (t0 + t)) * In + cc] : 0.f;
        }

        // ================= layer 0 =================
        {
            asm volatile("" ::: "memory");   // keep weight loads inside the chunk loop
            // recurrent weights: rows g*64+u, k in [16s,16s+16)
            const float4* p0 = reinterpret_cast<const float4*>(w_hh0 + (size_t)(0*Hh+u)*Hh + ko);
            const float4* p1 = reinterpret_cast<const float4*>(w_hh0 + (size_t)(1*Hh+u)*Hh + ko);
            const float4* p2 = reinterpret_cast<const float4*>(w_hh0 + (size_t)(2*Hh+u)*Hh + ko);
            const float4* p3 = reinterpret_cast<const float4*>(w_hh0 + (size_t)(3*Hh+u)*Hh + ko);
            float4 wh00=p0[0], wh01=p0[1], wh02=p0[2], wh03=p0[3];
            float4 wh10=p1[0], wh11=p1[1], wh12=p1[2], wh13=p1[3];
            float4 wh20=p2[0], wh21=p2[1], wh22=p2[2], wh23=p2[3];
            float4 wh30=p3[0], wh31=p3[1], wh32=p3[2], wh33=p3[3];
            // input weights (5 wide, rows not 16B-aligned): scalar loads, s==0 only
            float4 wx0={0,0,0,0}, wx1={0,0,0,0}, wx2={0,0,0,0}, wx3={0,0,0,0};
            float wq0=0.f, wq1=0.f, wq2=0.f, wq3=0.f;
            if (s == 0) {
                const float* q0 = w_ih0 + (0*Hh+u)*In;
                const float* q1 = w_ih0 + (1*Hh+u)*In;
                const float* q2 = w_ih0 + (2*Hh+u)*In;
                const float* q3 = w_ih0 + (3*Hh+u)*In;
                wx0 = make_float4(q0[0],q0[1],q0[2],q0[3]); wq0 = q0[4];
                wx1 = make_float4(q1[0],q1[1],q1[2],q1[3]); wq1 = q1[4];
                wx2 = make_float4(q2[0],q2[1],q2[2],q2[3]); wq2 = q2[4];
                wx3 = make_float4(q3[0],q3[1],q3[2],q3[3]); wq3 = q3[4];
            }
            const float bi0 = b_ih0[0*Hh+u] + b_hh0[0*Hh+u];
            const float bi1 = b_ih0[1*Hh+u] + b_hh0[1*Hh+u];
            const float bi2 = b_ih0[2*Hh+u] + b_hh0[2*Hh+u];
            const float bi3 = b_ih0[3*Hh+u] + b_hh0[3*Hh+u];
            __syncthreads();   // xs staged; buffers zeroed (chunk 0)

            #pragma unroll 1
            for (int tt = 0; tt < TC; ++tt) {
                const int tp = (tt == 0) ? (TC - 1) : (tt - 1);
                float a00=0.f,a10=0.f,a20=0.f,a30=0.f;   // gates i,f,g,o for b=0
                float a01=0.f,a11=0.f,a21=0.f,a31=0.f;   // for b=1
                DOT16(a00, wh00,wh01,wh02,wh03, &buf0[0][tp][ko]);
                DOT16(a10, wh10,wh11,wh12,wh13, &buf0[0][tp][ko]);
                DOT16(a20, wh20,wh21,wh22,wh23, &buf0[0][tp][ko]);
                DOT16(a30, wh30,wh31,wh32,wh33, &buf0[0][tp][ko]);
                DOT16(a01, wh00,wh01,wh02,wh03, &buf0[1][tp][ko]);
                DOT16(a11, wh10,wh11,wh12,wh13, &buf0[1][tp][ko]);
                DOT16(a21, wh20,wh21,wh22,wh23, &buf0[1][tp][ko]);
                DOT16(a31, wh30,wh31,wh32,wh33, &buf0[1][tp][ko]);
                {   // input contribution (weights zero for s!=0)
                    float4 xv0 = *reinterpret_cast<const float4*>(&xs[0][tt][0]);
                    float  xq0 = xs[0][tt][4];
                    float4 xv1 = *reinterpret_cast<const float4*>(&xs[1][tt][0]);
                    float  xq1 = xs[1][tt][4];
                    a00 += DOT4(wx0,xv0) + wq0*xq0;  a01 += DOT4(wx0,xv1) + wq0*xq1;
                    a10 += DOT4(wx1,xv0) + wq1*xq0;  a11 += DOT4(wx1,xv1) + wq1*xq1;
                    a20 += DOT4(wx2,xv0) + wq2*xq0;  a21 += DOT4(wx2,xv1) + wq2*xq1;
                    a30 += DOT4(wx3,xv0) + wq3*xq0;  a31 += DOT4(wx3,xv1) + wq3*xq1;
                }
                a00 = quad_sum(a00) + bi0;  a01 = quad_sum(a01) + bi0;
                a10 = quad_sum(a10) + bi1;  a11 = quad_sum(a11) + bi1;
                a20 = quad_sum(a20) + bi2;  a21 = quad_sum(a21) + bi2;
                a30 = quad_sum(a30) + bi3;  a31 = quad_sum(a31) + bi3;
                float i0 = sigm(a00), f0 = sigm(a10), g0 = tanh_fast(a20), o0 = sigm(a30);
                float i1 = sigm(a01), f1 = sigm(a11), g1 = tanh_fast(a21), o1 = sigm(a31);
                c00 = f0 * c00 + i0 * g0;
                c01 = f1 * c01 + i1 * g1;
                float h0 = o0 * tanh_fast(c00);
                float h1 = o1 * tanh_fast(c01);
                if (s == 0) { buf0[0][tt][u] = h0; buf0[1][tt][u] = h1; }
                __syncthreads();
            }
        }

        // ================= layer 1 =================
        {
            asm volatile("" ::: "memory");
            const float4* pi0 = reinterpret_cast<const float4*>(w_ih1 + (size_t)(0*Hh+u)*Hh + ko);
            const float4* pi1 = reinterpret_cast<const float4*>(w_ih1 + (size_t)(1*Hh+u)*Hh + ko);
            const float4* pi2 = reinterpret_cast<const float4*>(w_ih1 + (size_t)(2*Hh+u)*Hh + ko);
            const float4* pi3 = reinterpret_cast<const float4*>(w_ih1 + (size_t)(3*Hh+u)*Hh + ko);
            float4 wi00=pi0[0], wi01=pi0[1], wi02=pi0[2], wi03=pi0[3];
            float4 wi10=pi1[0], wi11=pi1[1], wi12=pi1[2], wi13=pi1[3];
            float4 wi20=pi2[0], wi21=pi2[1], wi22=pi2[2], wi23=pi2[3];
            float4 wi30=pi3[0], wi31=pi3[1], wi32=pi3[2], wi33=pi3[3];
            const float4* ph0 = reinterpret_cast<const float4*>(w_hh1 + (size_t)(0*Hh+u)*Hh + ko);
            const float4* ph1 = reinterpret_cast<const float4*>(w_hh1 + (size_t)(1*Hh+u)*Hh + ko);
            const float4* ph2 = reinterpret_cast<const float4*>(w_hh1 + (size_t)(2*Hh+u)*Hh + ko);
            const float4* ph3 = reinterpret_cast<const float4*>(w_hh1 + (size_t)(3*Hh+u)*Hh + ko);
            float4 wh00=ph0[0], wh01=ph0[1], wh02=ph0[2], wh03=ph0[3];
            float4 wh10=ph1[0], wh11=ph1[1], wh12=ph1[2], wh13=ph1[3];
            float4 wh20=ph2[0], wh21=ph2[1], wh22=ph2[2], wh23=ph2[3];
            float4 wh30=ph3[0], wh31=ph3[1], wh32=ph3[2], wh33=ph3[3];
            const float bi0 = b_ih1[0*Hh+u] + b_hh1[0*Hh+u];
            const float bi1 = b_ih1[1*Hh+u] + b_hh1[1*Hh+u];
            const float bi2 = b_ih1[2*Hh+u] + b_hh1[2*Hh+u];
            const float bi3 = b_ih1[3*Hh+u] + b_hh1[3*Hh+u];
            // buf0 chunk complete (final barrier of layer-0 loop)

            #pragma unroll 1
            for (int tt = 0; tt < TC; ++tt) {
                const int tp = (tt == 0) ? (TC - 1) : (tt - 1);
                float a00=0.f,a10=0.f,a20=0.f,a30=0.f;
                float a01=0.f,a11=0.f,a21=0.f,a31=0.f;
                DOT16(a00, wi00,wi01,wi02,wi03, &buf0[0][tt][ko]);
                DOT16(a10, wi10,wi11,wi12,wi13, &buf0[0][tt][ko]);
                DOT16(a20, wi20,wi21,wi22,wi23, &buf0[0][tt][ko]);
                DOT16(a30, wi30,wi31,wi32,wi33, &buf0[0][tt][ko]);
                DOT16(a00, wh00,wh01,wh02,wh03, &buf1[0][tp][ko]);
                DOT16(a10, wh10,wh11,wh12,wh13, &buf1[0][tp][ko]);
                DOT16(a20, wh20,wh21,wh22,wh23, &buf1[0][tp][ko]);
                DOT16(a30, wh30,wh31,wh32,wh33, &buf1[0][tp][ko]);
                DOT16(a01, wi00,wi01,wi02,wi03, &buf0[1][tt][ko]);
                DOT16(a11, wi10,wi11,wi12,wi13, &buf0[1][tt][ko]);
                DOT16(a21, wi20,wi21,wi22,wi23, &buf0[1][tt][ko]);
                DOT16(a31, wi30,wi31,wi32,wi33, &buf0[1][tt][ko]);
                DOT16(a01, wh00,wh01,wh02,wh03, &buf1[1][tp][ko]);
                DOT16(a11, wh10,wh11,wh12,wh13, &buf1[1][tp][ko]);
                DOT16(a21, wh20,wh21,wh22,wh23, &buf1[1][tp][ko]);
                DOT16(a31, wh30,wh31,wh32,wh33, &buf1[1][tp][ko]);
                a00 = quad_sum(a00) + bi0;  a01 = quad_sum(a01) + bi0;
                a10 = quad_sum(a10) + bi1;  a11 = quad_sum(a11) + bi1;
                a20 = quad_sum(a20) + bi2;  a21 = quad_sum(a21) + bi2;
                a30 = quad_sum(a30) + bi3;  a31 = quad_sum(a31) + bi3;
                float i0 = sigm(a00), f0 = sigm(a10), g0 = tanh_fast(a20), o0 = sigm(a30);
                float i1 = sigm(a01), f1 = sigm(a11), g1 = tanh_fast(a21), o1 = sigm(a31);
                c10 = f0 * c10 + i0 * g0;
                c11 = f1 * c11 + i1 * g1;
                float h0 = o0 * tanh_fast(c10);
                float h1 = o1 * tanh_fast(c11);
                if (s == 0) { buf1[0][tt][u] = h0; buf1[1][tt][u] = h1; }
                __syncthreads();
            }
        }

        // ================= layer 2 =================
        {
            asm volatile("" ::: "memory");
            const float4* pi0 = reinterpret_cast<const float4*>(w_ih2 + (size_t)(0*Hh+u)*Hh + ko);
            const float4* pi1 = reinterpret_cast<const float4*>(w_ih2 + (size_t)(1*Hh+u)*Hh + ko);
            const float4* pi2 = reinterpret_cast<const float4*>(w_ih2 + (size_t)(2*Hh+u)*Hh + ko);
            const float4* pi3 = reinterpret_cast<const float4*>(w_ih2 + (size_t)(3*Hh+u)*Hh + ko);
            float4 wi00=pi0[0], wi01=pi0[1], wi02=pi0[2], wi03=pi0[3];
            float4 wi10=pi1[0], wi11=pi1[1], wi12=pi1[2], wi13=pi1[3];
            float4 wi20=pi2[0], wi21=pi2[1], wi22=pi2[2], wi23=pi2[3];
            float4 wi30=pi3[0], wi31=pi3[1], wi32=pi3[2], wi33=pi3[3];
            const float4* ph0 = reinterpret_cast<const float4*>(w_hh2 + (size_t)(0*Hh+u)*Hh + ko);
            const float4* ph1 = reinterpret_cast<const float4*>(w_hh2 + (size_t)(1*Hh+u)*Hh + ko);
            const float4* ph2 = reinterpret_cast<const float4*>(w_hh2 + (size_t)(2*Hh+u)*Hh + ko);
            const float4* ph3 = reinterpret_cast<const float4*>(w_hh2 + (size_t)(3*Hh+u)*Hh + ko);
            float4 wh00=ph0[0], wh01=ph0[1], wh02=ph0[2], wh03=ph0[3];
            float4 wh10=ph1[0], wh11=ph1[1], wh12=ph1[2], wh13=ph1[3];
            float4 wh20=ph2[0], wh21=ph2[1], wh22=ph2[2], wh23=ph2[3];
            float4 wh30=ph3[0], wh31=ph3[1], wh32=ph3[2], wh33=ph3[3];
            const float bi0 = b_ih2[0*Hh+u] + b_hh2[0*Hh+u];
            const float bi1 = b_ih2[1*Hh+u] + b_hh2[1*Hh+u];
            const float bi2 = b_ih2[2*Hh+u] + b_hh2[2*Hh+u];
            const float bi3 = b_ih2[3*Hh+u] + b_hh2[3*Hh+u];

            #pragma unroll 1
            for (int tt = 0; tt < TC; ++tt) {
                const int ri = tt & 1, wri = ri ^ 1;   // rolling h2 parity
                float a00=0.f,a10=0.f,a20=0.f,a30=0.f;
                float a01=0.f,a11=0.f,a21=0.f,a31=0.f;
                DOT16(a00, wi00,wi01,wi02,wi03, &buf1[0][tt][ko]);
                DOT16(a10, wi10,wi11,wi12,wi13, &buf1[0][tt][ko]);
                DOT16(a20, wi20,wi21,wi22,wi23, &buf1[0][tt][ko]);
                DOT16(a30, wi30,wi31,wi32,wi33, &buf1[0][tt][ko]);
                DOT16(a00, wh00,wh01,wh02,wh03, &h2b[ri][0][ko]);
                DOT16(a10, wh10,wh11,wh12,wh13, &h2b[ri][0][ko]);
                DOT16(a20, wh20,wh21,wh22,wh23, &h2b[ri][0][ko]);
                DOT16(a30, wh30,wh31,wh32,wh33, &h2b[ri][0][ko]);
                DOT16(a01, wi00,wi01,wi02,wi03, &buf1[1][tt][ko]);
                DOT16(a11, wi10,wi11,wi12,wi13, &buf1[1][tt][ko]);
                DOT16(a21, wi20,wi21,wi22,wi23, &buf1[1][tt][ko]);
                DOT16(a31, wi30,wi31,wi32,wi33, &buf1[1][tt][ko]);
                DOT16(a01, wh00,wh01,wh02,wh03, &h2b[ri][1][ko]);
                DOT16(a11, wh10,wh11,wh12,wh13, &h2b[ri][1][ko]);
                DOT16(a21, wh20,wh21,wh22,wh23, &h2b[ri][1][ko]);
                DOT16(a31, wh30,wh31,wh32,wh33, &h2b[ri][1][ko]);
                a00 = quad_sum(a00) + bi0;  a01 = quad_sum(a01) + bi0;
                a10 = quad_sum(a10) + bi1;  a11 = quad_sum(a11) + bi1;
                a20 = quad_sum(a20) + bi2;  a21 = quad_sum(a21) + bi2;
                a30 = quad_sum(a30) + bi3;  a31 = quad_sum(a31) + bi3;
                float i0 = sigm(a00), f0 = sigm(a10), g0 = tanh_fast(a20), o0 = sigm(a30);
                float i1 = sigm(a01), f1 = sigm(a11), g1 = tanh_fast(a21), o1 = sigm(a31);
                c20 = f0 * c20 + i0 * g0;
                c21 = f1 * c21 + i1 * g1;
                float h0 = o0 * tanh_fast(c20);
                float h1 = o1 * tanh_fast(c21);
                if (s == 0) { h2b[wri][0][u] = h0; h2b[wri][1][u] = h1; }
                __syncthreads();
            }
        }
    }

    // ---- final FC on h2 at t = T-1 ----
    // last write index = ((TC-1)&1)^1 = 0
    if (tid < TB * Hh) {
        const int cb = tid >> 6, cu = tid & (Hh - 1);
        float p = h2b[0][cb][cu] * w_fc[cu];
        #pragma unroll
        for (int off = 32; off > 0; off >>= 1) p += __shfl_down(p, off, 64);
        if (cu == 0) out[b0 + cb] = p + b_fc[0];
    }
}

extern "C" void kernel_launch(void* const* d_in, const int* in_sizes, int n_in,
                              void* d_out, int out_size, void* d_ws, size_t ws_size,
                              hipStream_t stream) {
    const float* x     = (const float*)d_in[0];
    const float* w_ih0 = (const float*)d_in[1];
    const float* w_hh0 = (const float*)d_in[2];
    const float* b_ih0 = (const float*)d_in[3];
    const float* b_hh0 = (const float*)d_in[4];
    const float* w_ih1 = (const float*)d_in[5];
    const float* w_hh1 = (const float*)d_in[6];
    const float* b_ih1 = (const float*)d_in[7];
    const float* b_hh1 = (const float*)d_in[8];
    const float* w_ih2 = (const float*)d_in[9];
    const float* w_hh2 = (const float*)d_in[10];
    const float* b_ih2 = (const float*)d_in[11];
    const float* b_hh2 = (const float*)d_in[12];
    const float* w_fc  = (const float*)d_in[13];
    const float* b_fc  = (const float*)d_in[14];
    float* out = (float*)d_out;

    lstm3_fused<<<NB, NT, 0, stream>>>(x,
        w_ih0, w_hh0, b_ih0, b_hh0,
        w_ih1, w_hh1, b_ih1, b_hh1,
        w_ih2, w_hh2, b_ih2, b_hh2,
        w_fc, b_fc, out, Tt / TC);
}